// Round 4
// baseline (354.333 us; speedup 1.0000x reference)
//
#include <hip/hip_runtime.h>
#include <hip/hip_bf16.h>

#define EMBED 1024
#define HEADS 16
#define HD    64
#define NB    4
#define SEQ   2048

typedef __bf16 bf16x8 __attribute__((ext_vector_type(8)));
typedef float  f32x4  __attribute__((ext_vector_type(4)));

__device__ __forceinline__ unsigned short f2bf(float f) {
    union { float f; unsigned u; } v; v.f = f;
    unsigned r = v.u + 0x7fffu + ((v.u >> 16) & 1u);   // RNE, inputs finite
    return (unsigned short)(r >> 16);
}

// ---------------------------------------------------------------- Wo -> bf16
__global__ __launch_bounds__(256) void cvt_kernel(const float* __restrict__ src,
                                                  unsigned short* __restrict__ dst) {
    int i = blockIdx.x * 256 + threadIdx.x;
    float4 v = ((const float4*)src)[i];
    ushort4 o;
    o.x = f2bf(v.x); o.y = f2bf(v.y); o.z = f2bf(v.z); o.w = f2bf(v.w);
    ((ushort4*)dst)[i] = o;
}

// ------------------------------------------------------- Q/K/V projections
// p=0: query@Wq^T (softmax scale log2(e)/32 folded in) -> Qp [head][s][d]
// p=1: keys@Wk^T -> Kp [head][s][d]
// p=2: values@Wv^T -> Vt [head][d][s]
__global__ __launch_bounds__(256) void proj_kernel(
    const float* __restrict__ xq, const float* __restrict__ xk, const float* __restrict__ xv,
    const float* __restrict__ Wq, const float* __restrict__ Wk, const float* __restrict__ Wv,
    unsigned short* __restrict__ Qp, unsigned short* __restrict__ Kp, unsigned short* __restrict__ Vt)
{
    __shared__ __align__(16) unsigned short Wl[64 * 72];
    __shared__ __align__(16) unsigned short Xl[128 * 72];

    int bx = blockIdx.x;
    int p  = bx >> 10;
    int r  = bx & 1023;
    int st = r & 15, h = (r >> 4) & 15, n = r >> 8;
    int s0 = st * 128;

    const float* x = (p == 0) ? xq : (p == 1) ? xk : xv;
    const float* W = (p == 0) ? Wq : (p == 1) ? Wk : Wv;
    const float sc = (p == 0) ? 0.045084220027780106f : 1.0f;  // log2(e)/32

    int tid = threadIdx.x;

    for (int i = 0; i < 4; ++i) {
        int idx = tid + i * 256;
        int row = idx >> 4, c4 = idx & 15;
        float4 wv = ((const float4*)W)[row * 16 + c4];
        int o = row * 72 + c4 * 4;
        Wl[o] = f2bf(wv.x); Wl[o+1] = f2bf(wv.y); Wl[o+2] = f2bf(wv.z); Wl[o+3] = f2bf(wv.w);
    }
    const float* xbase = x + (size_t)(n * SEQ + s0) * EMBED + h * HD;
    for (int i = 0; i < 8; ++i) {
        int idx = tid + i * 256;
        int row = idx >> 4, c4 = idx & 15;
        float4 v = *(const float4*)(xbase + (size_t)row * EMBED + c4 * 4);
        int o = row * 72 + c4 * 4;
        Xl[o] = f2bf(v.x); Xl[o+1] = f2bf(v.y); Xl[o+2] = f2bf(v.z); Xl[o+3] = f2bf(v.w);
    }
    __syncthreads();

    int w = tid >> 6, lane = tid & 63, ln = lane & 15, qd = lane >> 4;

    bf16x8 a[2][2], b[4][2];
#pragma unroll
    for (int mt = 0; mt < 2; ++mt)
#pragma unroll
        for (int kt = 0; kt < 2; ++kt)
            a[mt][kt] = *(const bf16x8*)&Xl[(w * 32 + mt * 16 + ln) * 72 + kt * 32 + qd * 8];
#pragma unroll
    for (int nt = 0; nt < 4; ++nt)
#pragma unroll
        for (int kt = 0; kt < 2; ++kt)
            b[nt][kt] = *(const bf16x8*)&Wl[(nt * 16 + ln) * 72 + kt * 32 + qd * 8];

    f32x4 acc[2][4];
    const f32x4 fz = {0.f, 0.f, 0.f, 0.f};
#pragma unroll
    for (int mt = 0; mt < 2; ++mt)
#pragma unroll
        for (int nt = 0; nt < 4; ++nt) acc[mt][nt] = fz;
#pragma unroll
    for (int mt = 0; mt < 2; ++mt)
#pragma unroll
        for (int nt = 0; nt < 4; ++nt) {
            acc[mt][nt] = __builtin_amdgcn_mfma_f32_16x16x32_bf16(a[mt][0], b[nt][0], acc[mt][nt], 0, 0, 0);
            acc[mt][nt] = __builtin_amdgcn_mfma_f32_16x16x32_bf16(a[mt][1], b[nt][1], acc[mt][nt], 0, 0, 0);
        }
    __syncthreads();

    if (p < 2) {
#pragma unroll
        for (int mt = 0; mt < 2; ++mt)
#pragma unroll
            for (int nt = 0; nt < 4; ++nt)
#pragma unroll
                for (int rg = 0; rg < 4; ++rg)
                    Xl[(w * 32 + mt * 16 + qd * 4 + rg) * 72 + nt * 16 + ln] = f2bf(acc[mt][nt][rg] * sc);
        __syncthreads();
        unsigned short* outp = (p == 0 ? Qp : Kp) + (size_t)(n * HEADS + h) * SEQ * HD + (size_t)s0 * HD;
        for (int i = 0; i < 4; ++i) {
            int idx = tid + i * 256;
            int row = idx >> 3, ch = idx & 7;
            *(uint4*)(outp + (size_t)row * HD + ch * 8) = *(const uint4*)&Xl[row * 72 + ch * 8];
        }
    } else {
#pragma unroll
        for (int mt = 0; mt < 2; ++mt)
#pragma unroll
            for (int nt = 0; nt < 4; ++nt)
#pragma unroll
                for (int rg = 0; rg < 4; ++rg)
                    Xl[(nt * 16 + ln) * 136 + (w * 32 + mt * 16 + qd * 4 + rg)] = f2bf(acc[mt][nt][rg]);
        __syncthreads();
        unsigned short* outp = Vt + (size_t)(n * HEADS + h) * HD * SEQ + s0;
        for (int i = 0; i < 4; ++i) {
            int idx = tid + i * 256;
            int row = idx >> 4, ch = idx & 15;
            *(uint4*)(outp + (size_t)row * SEQ + ch * 8) = *(const uint4*)&Xl[row * 136 + ch * 8];
        }
    }
}

// ------------------------------------------------------------ flash attention
// q-tile 256 (64 rows/wave), double-buffered K/V staging via register prefetch,
// ONE barrier per 64-key chunk. l computed by MFMA against a ones-B fragment.
__global__ __launch_bounds__(256, 2) void attn_kernel(
    const unsigned short* __restrict__ Qp, const unsigned short* __restrict__ Kp,
    const unsigned short* __restrict__ Vt, unsigned short* __restrict__ Xattn)
{
    __shared__ __align__(16) unsigned short Kl[2][64 * 72];
    __shared__ __align__(16) unsigned short Vl[2][64 * 72];
    __shared__ __align__(16) unsigned short Pl[256 * 72];

    int bx = blockIdx.x;                 // 512 blocks: head*8 + qtile
    int head = bx >> 3, qt = bx & 7;
    int n = head >> 4, h = head & 15;
    int q0 = qt * 256;

    int tid = threadIdx.x;
    int w = tid >> 6, lane = tid & 63, ln = lane & 15, qd = lane >> 4;

    const unsigned short* Qb = Qp + (size_t)head * SEQ * HD;
    const unsigned short* Kb = Kp + (size_t)head * SEQ * HD;
    const unsigned short* Vb = Vt + (size_t)head * HD * SEQ;

    bf16x8 qa[4][2];
#pragma unroll
    for (int mt = 0; mt < 4; ++mt)
#pragma unroll
        for (int kt = 0; kt < 2; ++kt)
            qa[mt][kt] = *(const bf16x8*)(Qb + (size_t)(q0 + w * 64 + mt * 16 + ln) * HD + kt * 32 + qd * 8);

    const f32x4 fz = {0.f, 0.f, 0.f, 0.f};
    f32x4 o[4][4], l4[4];
#pragma unroll
    for (int mt = 0; mt < 4; ++mt) {
        l4[mt] = fz;
#pragma unroll
        for (int nt = 0; nt < 4; ++nt) o[mt][nt] = fz;
    }

    bf16x8 ones;
    {
        union { short s[8]; bf16x8 v; } uo;
#pragma unroll
        for (int i = 0; i < 8; ++i) uo.s[i] = 0x3F80;   // bf16 1.0
        ones = uo.v;
    }

    int srow = tid >> 3, sch = tid & 7;                  // staging: rows 0..31 (+32)
    int wsw = (qd & 2) << 3;                             // P-write col swizzle (row bit3)
    int rsw = (ln & 8) << 1;                             // P-read col swizzle

    // ---- prologue: chunk 0 -> regs -> buf0 ; chunk 1 -> regs
    uint4 rK[2], rV[2];
#pragma unroll
    for (int i = 0; i < 2; ++i) {
        int row = srow + i * 32;
        rK[i] = *(const uint4*)(Kb + (size_t)row * HD + sch * 8);
        rV[i] = *(const uint4*)(Vb + (size_t)row * SEQ + 0 + sch * 8);
    }
#pragma unroll
    for (int i = 0; i < 2; ++i) {
        int row = srow + i * 32;
        *(uint4*)&Kl[0][row * 72 + sch * 8] = rK[i];
        *(uint4*)&Vl[0][row * 72 + sch * 8] = rV[i];
    }
#pragma unroll
    for (int i = 0; i < 2; ++i) {
        int row = srow + i * 32;
        rK[i] = *(const uint4*)(Kb + (size_t)(64 + row) * HD + sch * 8);
        rV[i] = *(const uint4*)(Vb + (size_t)row * SEQ + 64 + sch * 8);
    }

    for (int kc = 0; kc < SEQ; kc += 64) {
        int cur = (kc >> 6) & 1, nxt = cur ^ 1;
        __syncthreads();   // chunk kc staged+visible; prior reads of buf[nxt] done

        if (kc + 64 < SEQ) {
            // write chunk kc+64 (in regs) into the other buffer
#pragma unroll
            for (int i = 0; i < 2; ++i) {
                int row = srow + i * 32;
                *(uint4*)&Kl[nxt][row * 72 + sch * 8] = rK[i];
                *(uint4*)&Vl[nxt][row * 72 + sch * 8] = rV[i];
            }
            // issue loads for chunk kc+128 (clamped; last chunk re-read harmlessly)
            int kn = kc + 128 <= SEQ - 64 ? kc + 128 : SEQ - 64;
#pragma unroll
            for (int i = 0; i < 2; ++i) {
                int row = srow + i * 32;
                rK[i] = *(const uint4*)(Kb + (size_t)(kn + row) * HD + sch * 8);
                rV[i] = *(const uint4*)(Vb + (size_t)row * SEQ + kn + sch * 8);
            }
        }

        // ---- S = Q K^T (scale pre-folded), exp2, stash P
        bf16x8 kb[4][2];
#pragma unroll
        for (int nt = 0; nt < 4; ++nt)
#pragma unroll
            for (int kt = 0; kt < 2; ++kt)
                kb[nt][kt] = *(const bf16x8*)&Kl[cur][(nt * 16 + ln) * 72 + kt * 32 + qd * 8];

#pragma unroll
        for (int mh = 0; mh < 2; ++mh) {
            f32x4 s[2][4];
#pragma unroll
            for (int m2 = 0; m2 < 2; ++m2)
#pragma unroll
                for (int nt = 0; nt < 4; ++nt) {
                    int mt = mh * 2 + m2;
                    f32x4 acc = fz;
                    acc = __builtin_amdgcn_mfma_f32_16x16x32_bf16(qa[mt][0], kb[nt][0], acc, 0, 0, 0);
                    acc = __builtin_amdgcn_mfma_f32_16x16x32_bf16(qa[mt][1], kb[nt][1], acc, 0, 0, 0);
                    s[m2][nt] = acc;
                }
#pragma unroll
            for (int m2 = 0; m2 < 2; ++m2)
#pragma unroll
                for (int nt = 0; nt < 4; ++nt) {
                    int mt = mh * 2 + m2;
                    int colsw = (nt * 16 + ln) ^ wsw;
#pragma unroll
                    for (int rg = 0; rg < 4; ++rg) {
                        float p = __builtin_amdgcn_exp2f(s[m2][nt][rg]);
                        union { float f; unsigned u; } c; c.f = p;
                        Pl[(w * 64 + mt * 16 + qd * 4 + rg) * 72 + colsw] =
                            (unsigned short)((c.u + 0x8000u) >> 16);
                    }
                }
        }
        __asm__ volatile("s_waitcnt lgkmcnt(0)" ::: "memory");

        // ---- O += P V ; l += P * ones
        bf16x8 pa[4][2], vf[4][2];
#pragma unroll
        for (int mt = 0; mt < 4; ++mt)
#pragma unroll
            for (int kt = 0; kt < 2; ++kt)
                pa[mt][kt] = *(const bf16x8*)&Pl[(w * 64 + mt * 16 + ln) * 72 + ((kt * 32 + qd * 8) ^ rsw)];
#pragma unroll
        for (int nt = 0; nt < 4; ++nt)
#pragma unroll
            for (int kt = 0; kt < 2; ++kt)
                vf[nt][kt] = *(const bf16x8*)&Vl[cur][(nt * 16 + ln) * 72 + kt * 32 + qd * 8];
#pragma unroll
        for (int mt = 0; mt < 4; ++mt) {
            l4[mt] = __builtin_amdgcn_mfma_f32_16x16x32_bf16(pa[mt][0], ones, l4[mt], 0, 0, 0);
            l4[mt] = __builtin_amdgcn_mfma_f32_16x16x32_bf16(pa[mt][1], ones, l4[mt], 0, 0, 0);
#pragma unroll
            for (int nt = 0; nt < 4; ++nt) {
                o[mt][nt] = __builtin_amdgcn_mfma_f32_16x16x32_bf16(pa[mt][0], vf[nt][0], o[mt][nt], 0, 0, 0);
                o[mt][nt] = __builtin_amdgcn_mfma_f32_16x16x32_bf16(pa[mt][1], vf[nt][1], o[mt][nt], 0, 0, 0);
            }
        }
    }

    // ---- normalize (l4[mt][rg] is the full row sum), stage, coalesced store
    __syncthreads();   // all chunk reads done; Pl reused for output staging
#pragma unroll
    for (int mt = 0; mt < 4; ++mt) {
        float inv[4];
#pragma unroll
        for (int rg = 0; rg < 4; ++rg) inv[rg] = 1.0f / l4[mt][rg];
#pragma unroll
        for (int nt = 0; nt < 4; ++nt)
#pragma unroll
            for (int rg = 0; rg < 4; ++rg)
                Pl[(w * 64 + mt * 16 + qd * 4 + rg) * 72 + nt * 16 + ln] = f2bf(o[mt][nt][rg] * inv[rg]);
    }
    __syncthreads();
    unsigned short* ob = Xattn + (size_t)(n * SEQ + q0) * EMBED + h * HD;
    for (int i = 0; i < 8; ++i) {
        int idx = tid + i * 256;                 // 256 rows x 8 chunks
        int row = idx >> 3, ch = idx & 7;
        *(uint4*)(ob + (size_t)row * EMBED + ch * 8) = *(const uint4*)&Pl[row * 72 + ch * 8];
    }
}

// ----------------------------------------------------- out = Xattn@Wo^T + bo
// Double-buffered reg-prefetch pipeline, one barrier per 64-k slab.
// Staging: 2 lanes/row, each lane covers 32 shorts = FOUR uint4 chunks.
__global__ __launch_bounds__(256, 2) void outproj_kernel(
    const unsigned short* __restrict__ X, const unsigned short* __restrict__ Wb,
    const float* __restrict__ bo, float* __restrict__ out)
{
    __shared__ __align__(16) unsigned short Al[2][128 * 72];
    __shared__ __align__(16) unsigned short Bl[2][128 * 72];

    int bx = blockIdx.x;
    int cm = bx >> 3, cn = bx & 7;
    int m0 = cm * 128, c0 = cn * 128;
    int tid = threadIdx.x;
    int w = tid >> 6, lane = tid & 63, ln = lane & 15, qd = lane >> 4;
    int rh = (w & 1) * 64, chh = (w >> 1) * 64;

    f32x4 acc[4][4];
    const f32x4 fz = {0.f, 0.f, 0.f, 0.f};
#pragma unroll
    for (int mt = 0; mt < 4; ++mt)
#pragma unroll
        for (int nt = 0; nt < 4; ++nt) acc[mt][nt] = fz;

    int srow = tid >> 1, sch = tid & 1;   // 128 rows x 2 lanes; 4 chunks of 8 shorts each

    uint4 rA[4], rB[4];
#pragma unroll
    for (int i = 0; i < 4; ++i) {
        rA[i] = *(const uint4*)(X  + (size_t)(m0 + srow) * EMBED + 0 + (sch * 4 + i) * 8);
        rB[i] = *(const uint4*)(Wb + (size_t)(c0 + srow) * EMBED + 0 + (sch * 4 + i) * 8);
    }
#pragma unroll
    for (int i = 0; i < 4; ++i) {
        *(uint4*)&Al[0][srow * 72 + (sch * 4 + i) * 8] = rA[i];
        *(uint4*)&Bl[0][srow * 72 + (sch * 4 + i) * 8] = rB[i];
    }
#pragma unroll
    for (int i = 0; i < 4; ++i) {
        rA[i] = *(const uint4*)(X  + (size_t)(m0 + srow) * EMBED + 64 + (sch * 4 + i) * 8);
        rB[i] = *(const uint4*)(Wb + (size_t)(c0 + srow) * EMBED + 64 + (sch * 4 + i) * 8);
    }

    for (int k0 = 0; k0 < EMBED; k0 += 64) {
        int cur = (k0 >> 6) & 1, nxt = cur ^ 1;
        __syncthreads();

        if (k0 + 64 < EMBED) {
#pragma unroll
            for (int i = 0; i < 4; ++i) {
                *(uint4*)&Al[nxt][srow * 72 + (sch * 4 + i) * 8] = rA[i];
                *(uint4*)&Bl[nxt][srow * 72 + (sch * 4 + i) * 8] = rB[i];
            }
            int kn = k0 + 128 <= EMBED - 64 ? k0 + 128 : EMBED - 64;
#pragma unroll
            for (int i = 0; i < 4; ++i) {
                rA[i] = *(const uint4*)(X  + (size_t)(m0 + srow) * EMBED + kn + (sch * 4 + i) * 8);
                rB[i] = *(const uint4*)(Wb + (size_t)(c0 + srow) * EMBED + kn + (sch * 4 + i) * 8);
            }
        }

        bf16x8 af[4][2], bf_[4][2];
#pragma unroll
        for (int mt = 0; mt < 4; ++mt)
#pragma unroll
            for (int kt = 0; kt < 2; ++kt)
                af[mt][kt] = *(const bf16x8*)&Al[cur][(rh + mt * 16 + ln) * 72 + kt * 32 + qd * 8];
#pragma unroll
        for (int nt = 0; nt < 4; ++nt)
#pragma unroll
            for (int kt = 0; kt < 2; ++kt)
                bf_[nt][kt] = *(const bf16x8*)&Bl[cur][(chh + nt * 16 + ln) * 72 + kt * 32 + qd * 8];
#pragma unroll
        for (int mt = 0; mt < 4; ++mt)
#pragma unroll
            for (int nt = 0; nt < 4; ++nt) {
                acc[mt][nt] = __builtin_amdgcn_mfma_f32_16x16x32_bf16(af[mt][0], bf_[nt][0], acc[mt][nt], 0, 0, 0);
                acc[mt][nt] = __builtin_amdgcn_mfma_f32_16x16x32_bf16(af[mt][1], bf_[nt][1], acc[mt][nt], 0, 0, 0);
            }
    }

#pragma unroll
    for (int nt = 0; nt < 4; ++nt) {
        int col = c0 + chh + nt * 16 + ln;
        float bias = bo[col];
#pragma unroll
        for (int mt = 0; mt < 4; ++mt) {
            int row = m0 + rh + mt * 16 + qd * 4;
#pragma unroll
            for (int rg = 0; rg < 4; ++rg)
                out[(size_t)(row + rg) * EMBED + col] = acc[mt][nt][rg] + bias;
        }
    }
}

// --------------------------------------------------------------------- launch
extern "C" void kernel_launch(void* const* d_in, const int* in_sizes, int n_in,
                              void* d_out, int out_size, void* d_ws, size_t ws_size,
                              hipStream_t stream) {
    const float* values = (const float*)d_in[0];
    const float* keys   = (const float*)d_in[1];
    const float* query  = (const float*)d_in[2];
    const float* Wv     = (const float*)d_in[3];
    const float* Wk     = (const float*)d_in[4];
    const float* Wq     = (const float*)d_in[5];
    const float* Wo     = (const float*)d_in[6];
    const float* bo     = (const float*)d_in[7];
    float* out = (float*)d_out;

    unsigned short* ws = (unsigned short*)d_ws;
    const size_t HSZ = (size_t)NB * HEADS * SEQ * HD;   // 8388608 elems
    unsigned short* Qp = ws;
    unsigned short* Kp = Qp + HSZ;
    unsigned short* Vt = Kp + HSZ;
    unsigned short* Xa = Vt + HSZ;
    unsigned short* Wb = Xa + HSZ;                       // 1024*1024 elems

    cvt_kernel<<<1024, 256, 0, stream>>>(Wo, Wb);
    proj_kernel<<<3072, 256, 0, stream>>>(query, keys, values, Wq, Wk, Wv, Qp, Kp, Vt);
    attn_kernel<<<512, 256, 0, stream>>>(Qp, Kp, Vt, Xa);
    outproj_kernel<<<512, 256, 0, stream>>>(Xa, Wb, bo, out);
}

// Round 5
// 304.032 us; speedup vs baseline: 1.1654x; 1.1654x over previous
//
#include <hip/hip_runtime.h>
#include <hip/hip_bf16.h>

#define EMBED 1024
#define HEADS 16
#define HD    64
#define NB    4
#define SEQ   2048

typedef __bf16 bf16x8 __attribute__((ext_vector_type(8)));
typedef float  f32x4  __attribute__((ext_vector_type(4)));

__device__ __forceinline__ unsigned short f2bf(float f) {
    union { float f; unsigned u; } v; v.f = f;
    unsigned r = v.u + 0x7fffu + ((v.u >> 16) & 1u);   // RNE, inputs finite
    return (unsigned short)(r >> 16);
}
__device__ __forceinline__ unsigned pack2(float a, float b) {
    return (unsigned)f2bf(a) | ((unsigned)f2bf(b) << 16);
}

// ---------------------------------------------------------------- Wo -> bf16
__global__ __launch_bounds__(256) void cvt_kernel(const float* __restrict__ src,
                                                  unsigned short* __restrict__ dst) {
    int i = blockIdx.x * 256 + threadIdx.x;
    float4 v = ((const float4*)src)[i];
    ushort4 o;
    o.x = f2bf(v.x); o.y = f2bf(v.y); o.z = f2bf(v.z); o.w = f2bf(v.w);
    ((ushort4*)dst)[i] = o;
}

// ------------------------------------------------------- Q/K/V projections
// 256 s-rows per block. p=0: query@Wq^T (scale log2(e)/32 folded) -> Qp [h][s][d]
// p=1: keys@Wk^T -> Kp [h][s][d]   p=2: values@Wv^T -> Vt [h][d][s]
__global__ __launch_bounds__(256) void proj_kernel(
    const float* __restrict__ xq, const float* __restrict__ xk, const float* __restrict__ xv,
    const float* __restrict__ Wq, const float* __restrict__ Wk, const float* __restrict__ Wv,
    unsigned short* __restrict__ Qp, unsigned short* __restrict__ Kp, unsigned short* __restrict__ Vt)
{
    __shared__ __align__(16) unsigned short Wl[64 * 72];
    __shared__ __align__(16) unsigned short Xl[256 * 72];   // x tile; reused for staging

    int bx = blockIdx.x;                  // 1536 = 3 * 512
    int p  = bx >> 9;
    int r  = bx & 511;
    int st = r & 7, h = (r >> 3) & 15, n = r >> 7;
    int s0 = st * 256;

    const float* x = (p == 0) ? xq : (p == 1) ? xk : xv;
    const float* W = (p == 0) ? Wq : (p == 1) ? Wk : Wv;
    const float sc = (p == 0) ? 0.045084220027780106f : 1.0f;  // log2(e)/32

    int tid = threadIdx.x;

    // stage W (64x64 fp32 -> bf16), row-major [e][d], stride 72
    for (int i = 0; i < 4; ++i) {
        int idx = tid + i * 256;
        int row = idx >> 4, c4 = idx & 15;
        float4 wv = ((const float4*)W)[row * 16 + c4];
        int o = row * 72 + c4 * 4;
        Wl[o] = f2bf(wv.x); Wl[o+1] = f2bf(wv.y); Wl[o+2] = f2bf(wv.z); Wl[o+3] = f2bf(wv.w);
    }
    // stage x tile (256 rows x 64 fp32 -> bf16), [s][d], stride 72
    const float* xbase = x + (size_t)(n * SEQ + s0) * EMBED + h * HD;
    for (int i = 0; i < 16; ++i) {
        int idx = tid + i * 256;
        int row = idx >> 4, c4 = idx & 15;
        float4 v = *(const float4*)(xbase + (size_t)row * EMBED + c4 * 4);
        int o = row * 72 + c4 * 4;
        Xl[o] = f2bf(v.x); Xl[o+1] = f2bf(v.y); Xl[o+2] = f2bf(v.z); Xl[o+3] = f2bf(v.w);
    }
    __syncthreads();

    int w = tid >> 6, lane = tid & 63, ln = lane & 15, qd = lane >> 4;

    bf16x8 a[4][2], b[4][2];                 // a: x rows (wave-private 64), b: W rows
#pragma unroll
    for (int mt = 0; mt < 4; ++mt)
#pragma unroll
        for (int kt = 0; kt < 2; ++kt)
            a[mt][kt] = *(const bf16x8*)&Xl[(w * 64 + mt * 16 + ln) * 72 + kt * 32 + qd * 8];
#pragma unroll
    for (int i = 0; i < 4; ++i)
#pragma unroll
        for (int kt = 0; kt < 2; ++kt)
            b[i][kt] = *(const bf16x8*)&Wl[(i * 16 + ln) * 72 + kt * 32 + qd * 8];

    f32x4 acc[4][4];
    const f32x4 fz = {0.f, 0.f, 0.f, 0.f};
#pragma unroll
    for (int i = 0; i < 4; ++i)
#pragma unroll
        for (int j = 0; j < 4; ++j) acc[i][j] = fz;

    if (p < 2) {
        // swapped: C[m=e][n=s] — lane col = s, rows = e (4 consecutive per qd)
#pragma unroll
        for (int i = 0; i < 4; ++i)
#pragma unroll
            for (int j = 0; j < 4; ++j) {
                acc[i][j] = __builtin_amdgcn_mfma_f32_16x16x32_bf16(b[i][0], a[j][0], acc[i][j], 0, 0, 0);
                acc[i][j] = __builtin_amdgcn_mfma_f32_16x16x32_bf16(b[i][1], a[j][1], acc[i][j], 0, 0, 0);
            }
        // stage [s][e], b64 packs (wave-private rows, no barrier needed)
#pragma unroll
        for (int i = 0; i < 4; ++i)
#pragma unroll
            for (int j = 0; j < 4; ++j) {
                uint2 pk;
                pk.x = pack2(acc[i][j][0] * sc, acc[i][j][1] * sc);
                pk.y = pack2(acc[i][j][2] * sc, acc[i][j][3] * sc);
                *(uint2*)&Xl[(w * 64 + j * 16 + ln) * 72 + i * 16 + qd * 4] = pk;
            }
        __syncthreads();
        unsigned short* outp = (p == 0 ? Qp : Kp) + (size_t)(n * HEADS + h) * SEQ * HD + (size_t)s0 * HD;
        for (int i = 0; i < 8; ++i) {
            int idx = tid + i * 256;                // 256 rows x 8 chunks
            int row = idx >> 3, ch = idx & 7;
            *(uint4*)(outp + (size_t)row * HD + ch * 8) = *(const uint4*)&Xl[row * 72 + ch * 8];
        }
    } else {
        // natural: C[m=s][n=e] — lane col = e, rows = s (4 consecutive per qd)
#pragma unroll
        for (int mt = 0; mt < 4; ++mt)
#pragma unroll
            for (int i = 0; i < 4; ++i) {
                acc[mt][i] = __builtin_amdgcn_mfma_f32_16x16x32_bf16(a[mt][0], b[i][0], acc[mt][i], 0, 0, 0);
                acc[mt][i] = __builtin_amdgcn_mfma_f32_16x16x32_bf16(a[mt][1], b[i][1], acc[mt][i], 0, 0, 0);
            }
        __syncthreads();   // all x reads done before transpose overwrite of Xl
        // stage V^T [e][s_local], stride 264, b64 packs
#pragma unroll
        for (int mt = 0; mt < 4; ++mt)
#pragma unroll
            for (int i = 0; i < 4; ++i) {
                uint2 pk;
                pk.x = pack2(acc[mt][i][0], acc[mt][i][1]);
                pk.y = pack2(acc[mt][i][2], acc[mt][i][3]);
                *(uint2*)&Xl[(i * 16 + ln) * 264 + w * 64 + mt * 16 + qd * 4] = pk;
            }
        __syncthreads();
        unsigned short* outp = Vt + (size_t)(n * HEADS + h) * HD * SEQ + s0;
        for (int i = 0; i < 8; ++i) {
            int idx = tid + i * 256;                // 64 rows x 32 chunks
            int row = idx >> 5, ch = idx & 31;
            *(uint4*)(outp + (size_t)row * SEQ + ch * 8) = *(const uint4*)&Xl[row * 264 + ch * 8];
        }
    }
}

// ------------------------------------------------------------ flash attention
// Operand-swapped: S^T = K Q^T (C: col=q, row=key) so P stores are b64-packed;
// O^T = V^T P^T (B = P^T read b128 from Pl[q][key]); l via ones-A MFMA
// (lane-aligned with q, no shuffles). K/V dbuf reg-prefetch, 1 barrier/chunk.
__global__ __launch_bounds__(256, 2) void attn_kernel(
    const unsigned short* __restrict__ Qp, const unsigned short* __restrict__ Kp,
    const unsigned short* __restrict__ Vt, unsigned short* __restrict__ Xattn)
{
    __shared__ __align__(16) unsigned short Kl[2][64 * 72];   // [key][d]
    __shared__ __align__(16) unsigned short Vl[2][64 * 72];   // [d][key]
    __shared__ __align__(16) unsigned short Pl[256 * 72];     // [q][key]; reused [q][d]

    int bx = blockIdx.x;                 // 512 blocks: head*8 + qtile
    int head = bx >> 3, qt = bx & 7;
    int n = head >> 4, h = head & 15;
    int q0 = qt * 256;

    int tid = threadIdx.x;
    int w = tid >> 6, lane = tid & 63, ln = lane & 15, qd = lane >> 4;

    const unsigned short* Qb = Qp + (size_t)head * SEQ * HD;
    const unsigned short* Kb = Kp + (size_t)head * SEQ * HD;
    const unsigned short* Vb = Vt + (size_t)head * HD * SEQ;

    // Q as B-operand: lane n=q holds d = qd*8.. (same bytes as row-major read)
    bf16x8 qb[4][2];
#pragma unroll
    for (int nt = 0; nt < 4; ++nt)
#pragma unroll
        for (int kt = 0; kt < 2; ++kt)
            qb[nt][kt] = *(const bf16x8*)(Qb + (size_t)(q0 + w * 64 + nt * 16 + ln) * HD + kt * 32 + qd * 8);

    const f32x4 fz = {0.f, 0.f, 0.f, 0.f};
    f32x4 ot[4][4], l4[4];               // ot[d-tile][q-tile]
#pragma unroll
    for (int mt = 0; mt < 4; ++mt) {
        l4[mt] = fz;
#pragma unroll
        for (int nt = 0; nt < 4; ++nt) ot[mt][nt] = fz;
    }

    bf16x8 ones;
    {
        union { short s[8]; bf16x8 v; } uo;
#pragma unroll
        for (int i = 0; i < 8; ++i) uo.s[i] = 0x3F80;   // bf16 1.0
        ones = uo.v;
    }

    int srow = tid >> 3, sch = tid & 7;                  // staging rows 0..31 (+32)

    // ---- prologue: chunk 0 -> regs -> buf0 ; chunk 1 -> regs
    uint4 rK[2], rV[2];
#pragma unroll
    for (int i = 0; i < 2; ++i) {
        int row = srow + i * 32;
        rK[i] = *(const uint4*)(Kb + (size_t)row * HD + sch * 8);
        rV[i] = *(const uint4*)(Vb + (size_t)row * SEQ + 0 + sch * 8);
    }
#pragma unroll
    for (int i = 0; i < 2; ++i) {
        int row = srow + i * 32;
        *(uint4*)&Kl[0][row * 72 + sch * 8] = rK[i];
        *(uint4*)&Vl[0][row * 72 + sch * 8] = rV[i];
    }
#pragma unroll
    for (int i = 0; i < 2; ++i) {
        int row = srow + i * 32;
        rK[i] = *(const uint4*)(Kb + (size_t)(64 + row) * HD + sch * 8);
        rV[i] = *(const uint4*)(Vb + (size_t)row * SEQ + 64 + sch * 8);
    }

    for (int kc = 0; kc < SEQ; kc += 64) {
        int cur = (kc >> 6) & 1, nxt = cur ^ 1;
        __syncthreads();   // chunk kc staged+visible; prior reads of buf[nxt] done

        if (kc + 64 < SEQ) {
#pragma unroll
            for (int i = 0; i < 2; ++i) {
                int row = srow + i * 32;
                *(uint4*)&Kl[nxt][row * 72 + sch * 8] = rK[i];
                *(uint4*)&Vl[nxt][row * 72 + sch * 8] = rV[i];
            }
            int kn = kc + 128 <= SEQ - 64 ? kc + 128 : SEQ - 64;
#pragma unroll
            for (int i = 0; i < 2; ++i) {
                int row = srow + i * 32;
                rK[i] = *(const uint4*)(Kb + (size_t)(kn + row) * HD + sch * 8);
                rV[i] = *(const uint4*)(Vb + (size_t)row * SEQ + kn + sch * 8);
            }
        }

        // ---- S^T = K Q^T ; P = exp2(S^T) -> Pl[q][key] via b64 packs
        bf16x8 kb[4][2];                 // A-operand: lane m=key
#pragma unroll
        for (int mt = 0; mt < 4; ++mt)
#pragma unroll
            for (int kt = 0; kt < 2; ++kt)
                kb[mt][kt] = *(const bf16x8*)&Kl[cur][(mt * 16 + ln) * 72 + kt * 32 + qd * 8];

#pragma unroll
        for (int mh = 0; mh < 2; ++mh) {
            f32x4 st[2][4];
#pragma unroll
            for (int m2 = 0; m2 < 2; ++m2)
#pragma unroll
                for (int nt = 0; nt < 4; ++nt) {
                    int mt = mh * 2 + m2;
                    f32x4 acc = fz;
                    acc = __builtin_amdgcn_mfma_f32_16x16x32_bf16(kb[mt][0], qb[nt][0], acc, 0, 0, 0);
                    acc = __builtin_amdgcn_mfma_f32_16x16x32_bf16(kb[mt][1], qb[nt][1], acc, 0, 0, 0);
                    st[m2][nt] = acc;
                }
#pragma unroll
            for (int m2 = 0; m2 < 2; ++m2)
#pragma unroll
                for (int nt = 0; nt < 4; ++nt) {
                    int mt = mh * 2 + m2;
                    float p0 = __builtin_amdgcn_exp2f(st[m2][nt][0]);
                    float p1 = __builtin_amdgcn_exp2f(st[m2][nt][1]);
                    float p2 = __builtin_amdgcn_exp2f(st[m2][nt][2]);
                    float p3 = __builtin_amdgcn_exp2f(st[m2][nt][3]);
                    uint2 pk;
                    pk.x = pack2(p0, p1);
                    pk.y = pack2(p2, p3);
                    // row q = w*64+nt*16+ln ; cols key = mt*16+qd*4 .. +3
                    *(uint2*)&Pl[(w * 64 + nt * 16 + ln) * 72 + mt * 16 + qd * 4] = pk;
                }
        }
        __asm__ volatile("s_waitcnt lgkmcnt(0)" ::: "memory");

        // ---- O^T += V^T P^T ; l += ones * P^T   (all b128 reads)
        bf16x8 pb[4][2], vf[4][2];
#pragma unroll
        for (int nt = 0; nt < 4; ++nt)
#pragma unroll
            for (int kt = 0; kt < 2; ++kt)
                pb[nt][kt] = *(const bf16x8*)&Pl[(w * 64 + nt * 16 + ln) * 72 + kt * 32 + qd * 8];
#pragma unroll
        for (int mt = 0; mt < 4; ++mt)
#pragma unroll
            for (int kt = 0; kt < 2; ++kt)
                vf[mt][kt] = *(const bf16x8*)&Vl[cur][(mt * 16 + ln) * 72 + kt * 32 + qd * 8];
#pragma unroll
        for (int nt = 0; nt < 4; ++nt) {
            l4[nt] = __builtin_amdgcn_mfma_f32_16x16x32_bf16(ones, pb[nt][0], l4[nt], 0, 0, 0);
            l4[nt] = __builtin_amdgcn_mfma_f32_16x16x32_bf16(ones, pb[nt][1], l4[nt], 0, 0, 0);
#pragma unroll
            for (int mt = 0; mt < 4; ++mt) {
                ot[mt][nt] = __builtin_amdgcn_mfma_f32_16x16x32_bf16(vf[mt][0], pb[nt][0], ot[mt][nt], 0, 0, 0);
                ot[mt][nt] = __builtin_amdgcn_mfma_f32_16x16x32_bf16(vf[mt][1], pb[nt][1], ot[mt][nt], 0, 0, 0);
            }
        }
    }

    // ---- normalize: l4[nt] regs all equal the row sum for this lane's q
    float inv[4];
#pragma unroll
    for (int nt = 0; nt < 4; ++nt) inv[nt] = 1.0f / l4[nt][0];

    // stage O [q][d] (b64 packs, wave-private rows), then coalesced store
#pragma unroll
    for (int mt = 0; mt < 4; ++mt)
#pragma unroll
        for (int nt = 0; nt < 4; ++nt) {
            uint2 pk;
            pk.x = pack2(ot[mt][nt][0] * inv[nt], ot[mt][nt][1] * inv[nt]);
            pk.y = pack2(ot[mt][nt][2] * inv[nt], ot[mt][nt][3] * inv[nt]);
            *(uint2*)&Pl[(w * 64 + nt * 16 + ln) * 72 + mt * 16 + qd * 4] = pk;
        }
    __syncthreads();
    unsigned short* ob = Xattn + (size_t)(n * SEQ + q0) * EMBED + h * HD;
    for (int i = 0; i < 8; ++i) {
        int idx = tid + i * 256;                 // 256 rows x 8 chunks
        int row = idx >> 3, ch = idx & 7;
        *(uint4*)(ob + (size_t)row * EMBED + ch * 8) = *(const uint4*)&Pl[row * 72 + ch * 8];
    }
}

// ----------------------------------------------------- out = Xattn@Wo^T + bo
// R2 version: simple 2-barrier loop, 36 KB LDS, 4 blocks/CU.
__global__ __launch_bounds__(256) void outproj_kernel(
    const unsigned short* __restrict__ X, const unsigned short* __restrict__ Wb,
    const float* __restrict__ bo, float* __restrict__ out)
{
    __shared__ __align__(16) unsigned short Al[128 * 72];
    __shared__ __align__(16) unsigned short Bl[128 * 72];

    int bx = blockIdx.x;
    int cm = bx >> 3, cn = bx & 7;
    int m0 = cm * 128, c0 = cn * 128;
    int tid = threadIdx.x;
    int w = tid >> 6, lane = tid & 63, ln = lane & 15, qd = lane >> 4;
    int rh = (w & 1) * 64, chh = (w >> 1) * 64;

    f32x4 acc[4][4];
    const f32x4 fz = {0.f, 0.f, 0.f, 0.f};
#pragma unroll
    for (int mt = 0; mt < 4; ++mt)
#pragma unroll
        for (int nt = 0; nt < 4; ++nt) acc[mt][nt] = fz;

    for (int k0 = 0; k0 < EMBED; k0 += 64) {
        for (int i = 0; i < 4; ++i) {
            int idx = tid + i * 256;
            int row = idx >> 3, ch = idx & 7;
            uint4 av = *(const uint4*)(X  + (size_t)(m0 + row) * EMBED + k0 + ch * 8);
            uint4 bv = *(const uint4*)(Wb + (size_t)(c0 + row) * EMBED + k0 + ch * 8);
            *(uint4*)&Al[row * 72 + ch * 8] = av;
            *(uint4*)&Bl[row * 72 + ch * 8] = bv;
        }
        __syncthreads();
        bf16x8 af[4][2], bf_[4][2];
#pragma unroll
        for (int mt = 0; mt < 4; ++mt)
#pragma unroll
            for (int kt = 0; kt < 2; ++kt)
                af[mt][kt] = *(const bf16x8*)&Al[(rh + mt * 16 + ln) * 72 + kt * 32 + qd * 8];
#pragma unroll
        for (int nt = 0; nt < 4; ++nt)
#pragma unroll
            for (int kt = 0; kt < 2; ++kt)
                bf_[nt][kt] = *(const bf16x8*)&Bl[(chh + nt * 16 + ln) * 72 + kt * 32 + qd * 8];
#pragma unroll
        for (int mt = 0; mt < 4; ++mt)
#pragma unroll
            for (int nt = 0; nt < 4; ++nt) {
                acc[mt][nt] = __builtin_amdgcn_mfma_f32_16x16x32_bf16(af[mt][0], bf_[nt][0], acc[mt][nt], 0, 0, 0);
                acc[mt][nt] = __builtin_amdgcn_mfma_f32_16x16x32_bf16(af[mt][1], bf_[nt][1], acc[mt][nt], 0, 0, 0);
            }
        __syncthreads();
    }

#pragma unroll
    for (int nt = 0; nt < 4; ++nt) {
        int col = c0 + chh + nt * 16 + ln;
        float bias = bo[col];
#pragma unroll
        for (int mt = 0; mt < 4; ++mt) {
            int row = m0 + rh + mt * 16 + qd * 4;
#pragma unroll
            for (int rg = 0; rg < 4; ++rg)
                out[(size_t)(row + rg) * EMBED + col] = acc[mt][nt][rg] + bias;
        }
    }
}

// --------------------------------------------------------------------- launch
extern "C" void kernel_launch(void* const* d_in, const int* in_sizes, int n_in,
                              void* d_out, int out_size, void* d_ws, size_t ws_size,
                              hipStream_t stream) {
    const float* values = (const float*)d_in[0];
    const float* keys   = (const float*)d_in[1];
    const float* query  = (const float*)d_in[2];
    const float* Wv     = (const float*)d_in[3];
    const float* Wk     = (const float*)d_in[4];
    const float* Wq     = (const float*)d_in[5];
    const float* Wo     = (const float*)d_in[6];
    const float* bo     = (const float*)d_in[7];
    float* out = (float*)d_out;

    unsigned short* ws = (unsigned short*)d_ws;
    const size_t HSZ = (size_t)NB * HEADS * SEQ * HD;   // 8388608 elems
    unsigned short* Qp = ws;
    unsigned short* Kp = Qp + HSZ;
    unsigned short* Vt = Kp + HSZ;
    unsigned short* Xa = Vt + HSZ;
    unsigned short* Wb = Xa + HSZ;                       // 1024*1024 elems

    cvt_kernel<<<1024, 256, 0, stream>>>(Wo, Wb);
    proj_kernel<<<1536, 256, 0, stream>>>(query, keys, values, Wq, Wk, Wv, Qp, Kp, Vt);
    attn_kernel<<<512, 256, 0, stream>>>(Qp, Kp, Vt, Xa);
    outproj_kernel<<<512, 256, 0, stream>>>(Xa, Wb, bo, out);
}

// Round 6
// 277.820 us; speedup vs baseline: 1.2754x; 1.0944x over previous
//
#include <hip/hip_runtime.h>
#include <hip/hip_bf16.h>

#define EMBED 1024
#define HEADS 16
#define HD    64
#define NB    4
#define SEQ   2048

typedef __bf16 bf16x8 __attribute__((ext_vector_type(8)));
typedef float  f32x4  __attribute__((ext_vector_type(4)));
typedef float  f32x16 __attribute__((ext_vector_type(16)));

__device__ __forceinline__ unsigned short f2bf(float f) {
    union { float f; unsigned u; } v; v.f = f;
    unsigned r = v.u + 0x7fffu + ((v.u >> 16) & 1u);   // RNE, inputs finite
    return (unsigned short)(r >> 16);
}
__device__ __forceinline__ unsigned pack2(float a, float b) {
    return (unsigned)f2bf(a) | ((unsigned)f2bf(b) << 16);
}

// ---------------------------------------------------------------- Wo -> bf16
__global__ __launch_bounds__(256) void cvt_kernel(const float* __restrict__ src,
                                                  unsigned short* __restrict__ dst) {
    int i = blockIdx.x * 256 + threadIdx.x;
    float4 v = ((const float4*)src)[i];
    ushort4 o;
    o.x = f2bf(v.x); o.y = f2bf(v.y); o.z = f2bf(v.z); o.w = f2bf(v.w);
    ((ushort4*)dst)[i] = o;
}

// ------------------------------------------------------- Q/K/V projections
// 256 s-rows per block. p=0: query@Wq^T (scale log2(e)/32 folded) -> Qp [h][s][d]
// p=1: keys@Wk^T -> Kp [h][s][d]   p=2: values@Wv^T -> Vt [h][d][s]
__global__ __launch_bounds__(256) void proj_kernel(
    const float* __restrict__ xq, const float* __restrict__ xk, const float* __restrict__ xv,
    const float* __restrict__ Wq, const float* __restrict__ Wk, const float* __restrict__ Wv,
    unsigned short* __restrict__ Qp, unsigned short* __restrict__ Kp, unsigned short* __restrict__ Vt)
{
    __shared__ __align__(16) unsigned short Wl[64 * 72];
    __shared__ __align__(16) unsigned short Xl[256 * 72];

    int bx = blockIdx.x;                  // 1536 = 3 * 512
    int p  = bx >> 9;
    int r  = bx & 511;
    int st = r & 7, h = (r >> 3) & 15, n = r >> 7;
    int s0 = st * 256;

    const float* x = (p == 0) ? xq : (p == 1) ? xk : xv;
    const float* W = (p == 0) ? Wq : (p == 1) ? Wk : Wv;
    const float sc = (p == 0) ? 0.045084220027780106f : 1.0f;  // log2(e)/32

    int tid = threadIdx.x;

    for (int i = 0; i < 4; ++i) {
        int idx = tid + i * 256;
        int row = idx >> 4, c4 = idx & 15;
        float4 wv = ((const float4*)W)[row * 16 + c4];
        int o = row * 72 + c4 * 4;
        Wl[o] = f2bf(wv.x); Wl[o+1] = f2bf(wv.y); Wl[o+2] = f2bf(wv.z); Wl[o+3] = f2bf(wv.w);
    }
    const float* xbase = x + (size_t)(n * SEQ + s0) * EMBED + h * HD;
    for (int i = 0; i < 16; ++i) {
        int idx = tid + i * 256;
        int row = idx >> 4, c4 = idx & 15;
        float4 v = *(const float4*)(xbase + (size_t)row * EMBED + c4 * 4);
        int o = row * 72 + c4 * 4;
        Xl[o] = f2bf(v.x); Xl[o+1] = f2bf(v.y); Xl[o+2] = f2bf(v.z); Xl[o+3] = f2bf(v.w);
    }
    __syncthreads();

    int w = tid >> 6, lane = tid & 63, ln = lane & 15, qd = lane >> 4;

    bf16x8 a[4][2], b[4][2];
#pragma unroll
    for (int mt = 0; mt < 4; ++mt)
#pragma unroll
        for (int kt = 0; kt < 2; ++kt)
            a[mt][kt] = *(const bf16x8*)&Xl[(w * 64 + mt * 16 + ln) * 72 + kt * 32 + qd * 8];
#pragma unroll
    for (int i = 0; i < 4; ++i)
#pragma unroll
        for (int kt = 0; kt < 2; ++kt)
            b[i][kt] = *(const bf16x8*)&Wl[(i * 16 + ln) * 72 + kt * 32 + qd * 8];

    f32x4 acc[4][4];
    const f32x4 fz = {0.f, 0.f, 0.f, 0.f};
#pragma unroll
    for (int i = 0; i < 4; ++i)
#pragma unroll
        for (int j = 0; j < 4; ++j) acc[i][j] = fz;

    if (p < 2) {
#pragma unroll
        for (int i = 0; i < 4; ++i)
#pragma unroll
            for (int j = 0; j < 4; ++j) {
                acc[i][j] = __builtin_amdgcn_mfma_f32_16x16x32_bf16(b[i][0], a[j][0], acc[i][j], 0, 0, 0);
                acc[i][j] = __builtin_amdgcn_mfma_f32_16x16x32_bf16(b[i][1], a[j][1], acc[i][j], 0, 0, 0);
            }
#pragma unroll
        for (int i = 0; i < 4; ++i)
#pragma unroll
            for (int j = 0; j < 4; ++j) {
                uint2 pk;
                pk.x = pack2(acc[i][j][0] * sc, acc[i][j][1] * sc);
                pk.y = pack2(acc[i][j][2] * sc, acc[i][j][3] * sc);
                *(uint2*)&Xl[(w * 64 + j * 16 + ln) * 72 + i * 16 + qd * 4] = pk;
            }
        __syncthreads();
        unsigned short* outp = (p == 0 ? Qp : Kp) + (size_t)(n * HEADS + h) * SEQ * HD + (size_t)s0 * HD;
        for (int i = 0; i < 8; ++i) {
            int idx = tid + i * 256;
            int row = idx >> 3, ch = idx & 7;
            *(uint4*)(outp + (size_t)row * HD + ch * 8) = *(const uint4*)&Xl[row * 72 + ch * 8];
        }
    } else {
#pragma unroll
        for (int mt = 0; mt < 4; ++mt)
#pragma unroll
            for (int i = 0; i < 4; ++i) {
                acc[mt][i] = __builtin_amdgcn_mfma_f32_16x16x32_bf16(a[mt][0], b[i][0], acc[mt][i], 0, 0, 0);
                acc[mt][i] = __builtin_amdgcn_mfma_f32_16x16x32_bf16(a[mt][1], b[i][1], acc[mt][i], 0, 0, 0);
            }
        __syncthreads();
#pragma unroll
        for (int mt = 0; mt < 4; ++mt)
#pragma unroll
            for (int i = 0; i < 4; ++i) {
                uint2 pk;
                pk.x = pack2(acc[mt][i][0], acc[mt][i][1]);
                pk.y = pack2(acc[mt][i][2], acc[mt][i][3]);
                *(uint2*)&Xl[(i * 16 + ln) * 264 + w * 64 + mt * 16 + qd * 4] = pk;
            }
        __syncthreads();
        unsigned short* outp = Vt + (size_t)(n * HEADS + h) * HD * SEQ + s0;
        for (int i = 0; i < 8; ++i) {
            int idx = tid + i * 256;
            int row = idx >> 5, ch = idx & 31;
            *(uint4*)(outp + (size_t)row * SEQ + ch * 8) = *(const uint4*)&Xl[row * 264 + ch * 8];
        }
    }
}

// ------------------------------------------------------------ flash attention
// 32x32x16 MFMAs. S^T = K Q^T (C: col=q, row=key). P stays in REGISTERS:
// the PV B-fragment is assembled from the exp'd C-regs with shfl_xor(32) +
// cndmask (the layouts differ only across lane-halves). No P LDS round-trip,
// no mid-chunk lgkmcnt(0). LDS = K/V dbuf only (36 KB), unioned with the
// output staging buffer. 512 thr/block, 8 waves x 32 q-rows, 2 blocks/CU,
// 16 waves/CU.
__global__ __launch_bounds__(512, 4) void attn_kernel(
    const unsigned short* __restrict__ Qp, const unsigned short* __restrict__ Kp,
    const unsigned short* __restrict__ Vt, unsigned short* __restrict__ Xattn)
{
    __shared__ __align__(16) unsigned short SMEM[18432];   // 36,864 B
    unsigned short* Kl = SMEM;           // [2][64*72]  (key, d)
    unsigned short* Vl = SMEM + 9216;    // [2][64*72]  (d, key)

    int bx = blockIdx.x;                 // 512 blocks: head*8 + qtile
    int head = bx >> 3, qt = bx & 7;
    int n = head >> 4, h16 = head & 15;
    int q0 = qt * 256;

    int tid = threadIdx.x;
    int w = tid >> 6, lane = tid & 63;
    int qc = lane & 31, hh = lane >> 5;

    const unsigned short* Qb = Qp + (size_t)head * SEQ * HD;
    const unsigned short* Kb = Kp + (size_t)head * SEQ * HD;
    const unsigned short* Vb = Vt + (size_t)head * HD * SEQ;

    // Q as B-operand (32x32x16): lane n=q, k(d) = kk*16 + hh*8 + j
    bf16x8 qb[4];
    {
        int qrow = q0 + w * 32 + qc;
#pragma unroll
        for (int kk = 0; kk < 4; ++kk)
            qb[kk] = *(const bf16x8*)(Qb + (size_t)qrow * HD + kk * 16 + hh * 8);
    }

    f32x16 ot0, ot1;
#pragma unroll
    for (int i = 0; i < 16; ++i) { ot0[i] = 0.f; ot1[i] = 0.f; }
    float lsum = 0.f;

    int srow = tid >> 3, sch = tid & 7;      // staging: 64 rows x 8 chunks

    // prologue: chunk 0 -> regs -> buf0 ; chunk 1 -> regs
    uint4 rK, rV;
    rK = *(const uint4*)(Kb + (size_t)srow * HD + sch * 8);
    rV = *(const uint4*)(Vb + (size_t)srow * SEQ + 0 + sch * 8);
    *(uint4*)&Kl[srow * 72 + sch * 8] = rK;
    *(uint4*)&Vl[srow * 72 + sch * 8] = rV;
    rK = *(const uint4*)(Kb + (size_t)(64 + srow) * HD + sch * 8);
    rV = *(const uint4*)(Vb + (size_t)srow * SEQ + 64 + sch * 8);

    for (int kc = 0; kc < SEQ; kc += 64) {
        int cur = (kc >> 6) & 1, nxt = cur ^ 1;
        int curo = cur * 4608;
        __syncthreads();   // chunk kc staged+visible; prior reads of buf[nxt] done

        if (kc + 64 < SEQ) {
            *(uint4*)&Kl[nxt * 4608 + srow * 72 + sch * 8] = rK;
            *(uint4*)&Vl[nxt * 4608 + srow * 72 + sch * 8] = rV;
            int kn = kc + 128 <= SEQ - 64 ? kc + 128 : SEQ - 64;
            rK = *(const uint4*)(Kb + (size_t)(kn + srow) * HD + sch * 8);
            rV = *(const uint4*)(Vb + (size_t)srow * SEQ + kn + sch * 8);
        }

        // ---- S^T = K Q^T (32x32 tiles), exp2, pack to bf16 pairs in regs
        unsigned pk[2][8];
#pragma unroll
        for (int kt = 0; kt < 2; ++kt) {
            f32x16 c;
#pragma unroll
            for (int i = 0; i < 16; ++i) c[i] = 0.f;
#pragma unroll
            for (int kk = 0; kk < 4; ++kk) {
                bf16x8 ka = *(const bf16x8*)&Kl[curo + (kt * 32 + qc) * 72 + kk * 16 + hh * 8];
                c = __builtin_amdgcn_mfma_f32_32x32x16_bf16(ka, qb[kk], c, 0, 0, 0);
            }
#pragma unroll
            for (int i = 0; i < 8; ++i) {
                float p0 = __builtin_amdgcn_exp2f(c[2 * i]);
                float p1 = __builtin_amdgcn_exp2f(c[2 * i + 1]);
                lsum += p0 + p1;
                pk[kt][i] = pack2(p0, p1);
            }
        }

        // ---- O^T += V^T P^T : assemble B-frag per 16-key block via shfl_xor(32)
#pragma unroll
        for (int g = 0; g < 4; ++g) {
            const unsigned* P = pk[g >> 1];
            int base = (g & 1) * 4;
            unsigned s0 = hh ? P[base + 0] : P[base + 2];
            unsigned s1 = hh ? P[base + 1] : P[base + 3];
            unsigned r0 = (unsigned)__shfl_xor((int)s0, 32);
            unsigned r1 = (unsigned)__shfl_xor((int)s1, 32);
            union { unsigned u[4]; bf16x8 v; } bb;
            bb.u[0] = hh ? r0 : P[base + 0];
            bb.u[1] = hh ? r1 : P[base + 1];
            bb.u[2] = hh ? P[base + 2] : r0;
            bb.u[3] = hh ? P[base + 3] : r1;
            bf16x8 va0 = *(const bf16x8*)&Vl[curo + qc * 72 + g * 16 + hh * 8];
            bf16x8 va1 = *(const bf16x8*)&Vl[curo + (32 + qc) * 72 + g * 16 + hh * 8];
            ot0 = __builtin_amdgcn_mfma_f32_32x32x16_bf16(va0, bb.v, ot0, 0, 0, 0);
            ot1 = __builtin_amdgcn_mfma_f32_32x32x16_bf16(va1, bb.v, ot1, 0, 0, 0);
        }
    }

    // ---- finish l (other half of keys lives in the xor-32 partner)
    lsum += __shfl_xor(lsum, 32);
    float inv = 1.0f / lsum;

    // ---- stage O [q][d] into SMEM (reuses K/V space), coalesced store
    __syncthreads();
    int qlocal = w * 32 + qc;
#pragma unroll
    for (int dt = 0; dt < 2; ++dt) {
        const f32x16& o = dt ? ot1 : ot0;
#pragma unroll
        for (int g = 0; g < 4; ++g) {
            uint2 p;
            p.x = pack2(o[4 * g + 0] * inv, o[4 * g + 1] * inv);
            p.y = pack2(o[4 * g + 2] * inv, o[4 * g + 3] * inv);
            *(uint2*)&SMEM[qlocal * 72 + dt * 32 + g * 8 + hh * 4] = p;
        }
    }
    __syncthreads();
    unsigned short* ob = Xattn + (size_t)(n * SEQ + q0) * EMBED + h16 * HD;
#pragma unroll
    for (int i = 0; i < 4; ++i) {
        int idx = tid + i * 512;                 // 256 rows x 8 chunks
        int row = idx >> 3, ch = idx & 7;
        *(uint4*)(ob + (size_t)row * EMBED + ch * 8) = *(const uint4*)&SMEM[row * 72 + ch * 8];
    }
}

// ----------------------------------------------------- out = Xattn@Wo^T + bo
__global__ __launch_bounds__(256) void outproj_kernel(
    const unsigned short* __restrict__ X, const unsigned short* __restrict__ Wb,
    const float* __restrict__ bo, float* __restrict__ out)
{
    __shared__ __align__(16) unsigned short Al[128 * 72];
    __shared__ __align__(16) unsigned short Bl[128 * 72];

    int bx = blockIdx.x;
    int cm = bx >> 3, cn = bx & 7;
    int m0 = cm * 128, c0 = cn * 128;
    int tid = threadIdx.x;
    int w = tid >> 6, lane = tid & 63, ln = lane & 15, qd = lane >> 4;
    int rh = (w & 1) * 64, chh = (w >> 1) * 64;

    f32x4 acc[4][4];
    const f32x4 fz = {0.f, 0.f, 0.f, 0.f};
#pragma unroll
    for (int mt = 0; mt < 4; ++mt)
#pragma unroll
        for (int nt = 0; nt < 4; ++nt) acc[mt][nt] = fz;

    for (int k0 = 0; k0 < EMBED; k0 += 64) {
        for (int i = 0; i < 4; ++i) {
            int idx = tid + i * 256;
            int row = idx >> 3, ch = idx & 7;
            uint4 av = *(const uint4*)(X  + (size_t)(m0 + row) * EMBED + k0 + ch * 8);
            uint4 bv = *(const uint4*)(Wb + (size_t)(c0 + row) * EMBED + k0 + ch * 8);
            *(uint4*)&Al[row * 72 + ch * 8] = av;
            *(uint4*)&Bl[row * 72 + ch * 8] = bv;
        }
        __syncthreads();
        bf16x8 af[4][2], bf_[4][2];
#pragma unroll
        for (int mt = 0; mt < 4; ++mt)
#pragma unroll
            for (int kt = 0; kt < 2; ++kt)
                af[mt][kt] = *(const bf16x8*)&Al[(rh + mt * 16 + ln) * 72 + kt * 32 + qd * 8];
#pragma unroll
        for (int nt = 0; nt < 4; ++nt)
#pragma unroll
            for (int kt = 0; kt < 2; ++kt)
                bf_[nt][kt] = *(const bf16x8*)&Bl[(chh + nt * 16 + ln) * 72 + kt * 32 + qd * 8];
#pragma unroll
        for (int mt = 0; mt < 4; ++mt)
#pragma unroll
            for (int nt = 0; nt < 4; ++nt) {
                acc[mt][nt] = __builtin_amdgcn_mfma_f32_16x16x32_bf16(af[mt][0], bf_[nt][0], acc[mt][nt], 0, 0, 0);
                acc[mt][nt] = __builtin_amdgcn_mfma_f32_16x16x32_bf16(af[mt][1], bf_[nt][1], acc[mt][nt], 0, 0, 0);
            }
        __syncthreads();
    }

#pragma unroll
    for (int nt = 0; nt < 4; ++nt) {
        int col = c0 + chh + nt * 16 + ln;
        float bias = bo[col];
#pragma unroll
        for (int mt = 0; mt < 4; ++mt) {
            int row = m0 + rh + mt * 16 + qd * 4;
#pragma unroll
            for (int rg = 0; rg < 4; ++rg)
                out[(size_t)(row + rg) * EMBED + col] = acc[mt][nt][rg] + bias;
        }
    }
}

// --------------------------------------------------------------------- launch
extern "C" void kernel_launch(void* const* d_in, const int* in_sizes, int n_in,
                              void* d_out, int out_size, void* d_ws, size_t ws_size,
                              hipStream_t stream) {
    const float* values = (const float*)d_in[0];
    const float* keys   = (const float*)d_in[1];
    const float* query  = (const float*)d_in[2];
    const float* Wv     = (const float*)d_in[3];
    const float* Wk     = (const float*)d_in[4];
    const float* Wq     = (const float*)d_in[5];
    const float* Wo     = (const float*)d_in[6];
    const float* bo     = (const float*)d_in[7];
    float* out = (float*)d_out;

    unsigned short* ws = (unsigned short*)d_ws;
    const size_t HSZ = (size_t)NB * HEADS * SEQ * HD;   // 8388608 elems
    unsigned short* Qp = ws;
    unsigned short* Kp = Qp + HSZ;
    unsigned short* Vt = Kp + HSZ;
    unsigned short* Xa = Vt + HSZ;
    unsigned short* Wb = Xa + HSZ;                       // 1024*1024 elems

    cvt_kernel<<<1024, 256, 0, stream>>>(Wo, Wb);
    proj_kernel<<<1536, 256, 0, stream>>>(query, keys, values, Wq, Wk, Wv, Qp, Kp, Vt);
    attn_kernel<<<512, 512, 0, stream>>>(Qp, Kp, Vt, Xa);
    outproj_kernel<<<512, 256, 0, stream>>>(Xa, Wb, bo, out);
}

// Round 7
// 276.476 us; speedup vs baseline: 1.2816x; 1.0049x over previous
//
#include <hip/hip_runtime.h>
#include <hip/hip_bf16.h>

#define EMBED 1024
#define HEADS 16
#define HD    64
#define NB    4
#define SEQ   2048

typedef __bf16 bf16x2 __attribute__((ext_vector_type(2)));
typedef __bf16 bf16x8 __attribute__((ext_vector_type(8)));
typedef float  f32x4  __attribute__((ext_vector_type(4)));
typedef float  f32x16 __attribute__((ext_vector_type(16)));

__device__ __forceinline__ unsigned short f2bf(float f) {
    union { float f; unsigned u; } v; v.f = f;
    unsigned r = v.u + 0x7fffu + ((v.u >> 16) & 1u);   // RNE, inputs finite
    return (unsigned short)(r >> 16);
}
// packed 2xf32 -> bf16x2 (low=a, high=b). gfx950 has a 1-op HW converter.
__device__ __forceinline__ unsigned pack2(float a, float b) {
#if __has_builtin(__builtin_amdgcn_cvt_pk_bf16_f32)
    union { bf16x2 v; unsigned u; } c;
    c.v = __builtin_amdgcn_cvt_pk_bf16_f32(a, b);
    return c.u;
#else
    return (unsigned)f2bf(a) | ((unsigned)f2bf(b) << 16);
#endif
}

// ---------------------------------------------------------------- Wo -> bf16
__global__ __launch_bounds__(256) void cvt_kernel(const float* __restrict__ src,
                                                  unsigned* __restrict__ dst) {
    int i = blockIdx.x * 256 + threadIdx.x;
    float4 v = ((const float4*)src)[i];
    uint2 o;
    o.x = pack2(v.x, v.y);
    o.y = pack2(v.z, v.w);
    ((uint2*)dst)[i] = o;
}

// ------------------------------------------------------- Q/K/V projections
// 256 s-rows per block. p=0: query@Wq^T (scale log2(e)/32 folded) -> Qp [h][s][d]
// p=1: keys@Wk^T -> Kp [h][s][d]   p=2: values@Wv^T -> Vt [h][d][s]
__global__ __launch_bounds__(256) void proj_kernel(
    const float* __restrict__ xq, const float* __restrict__ xk, const float* __restrict__ xv,
    const float* __restrict__ Wq, const float* __restrict__ Wk, const float* __restrict__ Wv,
    unsigned short* __restrict__ Qp, unsigned short* __restrict__ Kp, unsigned short* __restrict__ Vt)
{
    __shared__ __align__(16) unsigned short Wl[64 * 72];
    __shared__ __align__(16) unsigned short Xl[256 * 72];

    int bx = blockIdx.x;                  // 1536 = 3 * 512
    int p  = bx >> 9;
    int r  = bx & 511;
    int st = r & 7, h = (r >> 3) & 15, n = r >> 7;
    int s0 = st * 256;

    const float* x = (p == 0) ? xq : (p == 1) ? xk : xv;
    const float* W = (p == 0) ? Wq : (p == 1) ? Wk : Wv;
    const float sc = (p == 0) ? 0.045084220027780106f : 1.0f;  // log2(e)/32

    int tid = threadIdx.x;

    for (int i = 0; i < 4; ++i) {
        int idx = tid + i * 256;
        int row = idx >> 4, c4 = idx & 15;
        float4 wv = ((const float4*)W)[row * 16 + c4];
        uint2 pw;
        pw.x = pack2(wv.x, wv.y);
        pw.y = pack2(wv.z, wv.w);
        *(uint2*)&Wl[row * 72 + c4 * 4] = pw;
    }
    const float* xbase = x + (size_t)(n * SEQ + s0) * EMBED + h * HD;
    for (int i = 0; i < 16; ++i) {
        int idx = tid + i * 256;
        int row = idx >> 4, c4 = idx & 15;
        float4 v = *(const float4*)(xbase + (size_t)row * EMBED + c4 * 4);
        uint2 px;
        px.x = pack2(v.x, v.y);
        px.y = pack2(v.z, v.w);
        *(uint2*)&Xl[row * 72 + c4 * 4] = px;
    }
    __syncthreads();

    int w = tid >> 6, lane = tid & 63, ln = lane & 15, qd = lane >> 4;

    bf16x8 a[4][2], b[4][2];
#pragma unroll
    for (int mt = 0; mt < 4; ++mt)
#pragma unroll
        for (int kt = 0; kt < 2; ++kt)
            a[mt][kt] = *(const bf16x8*)&Xl[(w * 64 + mt * 16 + ln) * 72 + kt * 32 + qd * 8];
#pragma unroll
    for (int i = 0; i < 4; ++i)
#pragma unroll
        for (int kt = 0; kt < 2; ++kt)
            b[i][kt] = *(const bf16x8*)&Wl[(i * 16 + ln) * 72 + kt * 32 + qd * 8];

    f32x4 acc[4][4];
    const f32x4 fz = {0.f, 0.f, 0.f, 0.f};
#pragma unroll
    for (int i = 0; i < 4; ++i)
#pragma unroll
        for (int j = 0; j < 4; ++j) acc[i][j] = fz;

    if (p < 2) {
#pragma unroll
        for (int i = 0; i < 4; ++i)
#pragma unroll
            for (int j = 0; j < 4; ++j) {
                acc[i][j] = __builtin_amdgcn_mfma_f32_16x16x32_bf16(b[i][0], a[j][0], acc[i][j], 0, 0, 0);
                acc[i][j] = __builtin_amdgcn_mfma_f32_16x16x32_bf16(b[i][1], a[j][1], acc[i][j], 0, 0, 0);
            }
#pragma unroll
        for (int i = 0; i < 4; ++i)
#pragma unroll
            for (int j = 0; j < 4; ++j) {
                uint2 pk;
                pk.x = pack2(acc[i][j][0] * sc, acc[i][j][1] * sc);
                pk.y = pack2(acc[i][j][2] * sc, acc[i][j][3] * sc);
                *(uint2*)&Xl[(w * 64 + j * 16 + ln) * 72 + i * 16 + qd * 4] = pk;
            }
        __syncthreads();
        unsigned short* outp = (p == 0 ? Qp : Kp) + (size_t)(n * HEADS + h) * SEQ * HD + (size_t)s0 * HD;
        for (int i = 0; i < 8; ++i) {
            int idx = tid + i * 256;
            int row = idx >> 3, ch = idx & 7;
            *(uint4*)(outp + (size_t)row * HD + ch * 8) = *(const uint4*)&Xl[row * 72 + ch * 8];
        }
    } else {
#pragma unroll
        for (int mt = 0; mt < 4; ++mt)
#pragma unroll
            for (int i = 0; i < 4; ++i) {
                acc[mt][i] = __builtin_amdgcn_mfma_f32_16x16x32_bf16(a[mt][0], b[i][0], acc[mt][i], 0, 0, 0);
                acc[mt][i] = __builtin_amdgcn_mfma_f32_16x16x32_bf16(a[mt][1], b[i][1], acc[mt][i], 0, 0, 0);
            }
        __syncthreads();
#pragma unroll
        for (int mt = 0; mt < 4; ++mt)
#pragma unroll
            for (int i = 0; i < 4; ++i) {
                uint2 pk;
                pk.x = pack2(acc[mt][i][0], acc[mt][i][1]);
                pk.y = pack2(acc[mt][i][2], acc[mt][i][3]);
                *(uint2*)&Xl[(i * 16 + ln) * 264 + w * 64 + mt * 16 + qd * 4] = pk;
            }
        __syncthreads();
        unsigned short* outp = Vt + (size_t)(n * HEADS + h) * HD * SEQ + s0;
        for (int i = 0; i < 8; ++i) {
            int idx = tid + i * 256;
            int row = idx >> 5, ch = idx & 31;
            *(uint4*)(outp + (size_t)row * SEQ + ch * 8) = *(const uint4*)&Xl[row * 264 + ch * 8];
        }
    }
}

// ------------------------------------------------------------ flash attention
// 32x32x16 MFMAs. S^T = K Q^T (C: col=q, row=key). P stays in REGISTERS:
// the PV B-fragment is assembled from the exp'd C-regs with shfl_xor(32) +
// cndmask. LDS = K/V dbuf only (36 KB), unioned with output staging.
// 512 thr/block, 8 waves x 32 q-rows.
__global__ __launch_bounds__(512, 4) void attn_kernel(
    const unsigned short* __restrict__ Qp, const unsigned short* __restrict__ Kp,
    const unsigned short* __restrict__ Vt, unsigned short* __restrict__ Xattn)
{
    __shared__ __align__(16) unsigned short SMEM[18432];   // 36,864 B
    unsigned short* Kl = SMEM;           // [2][64*72]  (key, d)
    unsigned short* Vl = SMEM + 9216;    // [2][64*72]  (d, key)

    int bx = blockIdx.x;                 // 512 blocks: head*8 + qtile
    int head = bx >> 3, qt = bx & 7;
    int n = head >> 4, h16 = head & 15;
    int q0 = qt * 256;

    int tid = threadIdx.x;
    int w = tid >> 6, lane = tid & 63;
    int qc = lane & 31, hh = lane >> 5;

    const unsigned short* Qb = Qp + (size_t)head * SEQ * HD;
    const unsigned short* Kb = Kp + (size_t)head * SEQ * HD;
    const unsigned short* Vb = Vt + (size_t)head * HD * SEQ;

    // Q as B-operand (32x32x16): lane n=q, k(d) = kk*16 + hh*8 + j
    bf16x8 qb[4];
    {
        int qrow = q0 + w * 32 + qc;
#pragma unroll
        for (int kk = 0; kk < 4; ++kk)
            qb[kk] = *(const bf16x8*)(Qb + (size_t)qrow * HD + kk * 16 + hh * 8);
    }

    f32x16 ot0, ot1;
#pragma unroll
    for (int i = 0; i < 16; ++i) { ot0[i] = 0.f; ot1[i] = 0.f; }
    float lsum = 0.f;

    int srow = tid >> 3, sch = tid & 7;      // staging: 64 rows x 8 chunks

    // prologue: chunk 0 -> regs -> buf0 ; chunk 1 -> regs
    uint4 rK, rV;
    rK = *(const uint4*)(Kb + (size_t)srow * HD + sch * 8);
    rV = *(const uint4*)(Vb + (size_t)srow * SEQ + 0 + sch * 8);
    *(uint4*)&Kl[srow * 72 + sch * 8] = rK;
    *(uint4*)&Vl[srow * 72 + sch * 8] = rV;
    rK = *(const uint4*)(Kb + (size_t)(64 + srow) * HD + sch * 8);
    rV = *(const uint4*)(Vb + (size_t)srow * SEQ + 64 + sch * 8);

    for (int kc = 0; kc < SEQ; kc += 64) {
        int cur = (kc >> 6) & 1, nxt = cur ^ 1;
        int curo = cur * 4608;
        __syncthreads();   // chunk kc staged+visible; prior reads of buf[nxt] done

        if (kc + 64 < SEQ) {
            *(uint4*)&Kl[nxt * 4608 + srow * 72 + sch * 8] = rK;
            *(uint4*)&Vl[nxt * 4608 + srow * 72 + sch * 8] = rV;
            int kn = kc + 128 <= SEQ - 64 ? kc + 128 : SEQ - 64;
            rK = *(const uint4*)(Kb + (size_t)(kn + srow) * HD + sch * 8);
            rV = *(const uint4*)(Vb + (size_t)srow * SEQ + kn + sch * 8);
        }

        // ---- S^T = K Q^T (32x32 tiles), exp2, pack to bf16 pairs in regs
        unsigned pk[2][8];
#pragma unroll
        for (int kt = 0; kt < 2; ++kt) {
            f32x16 c;
#pragma unroll
            for (int i = 0; i < 16; ++i) c[i] = 0.f;
#pragma unroll
            for (int kk = 0; kk < 4; ++kk) {
                bf16x8 ka = *(const bf16x8*)&Kl[curo + (kt * 32 + qc) * 72 + kk * 16 + hh * 8];
                c = __builtin_amdgcn_mfma_f32_32x32x16_bf16(ka, qb[kk], c, 0, 0, 0);
            }
#pragma unroll
            for (int i = 0; i < 8; ++i) {
                float p0 = __builtin_amdgcn_exp2f(c[2 * i]);
                float p1 = __builtin_amdgcn_exp2f(c[2 * i + 1]);
                lsum += p0 + p1;
                pk[kt][i] = pack2(p0, p1);
            }
        }

        // ---- O^T += V^T P^T : assemble B-frag per 16-key block via shfl_xor(32)
#pragma unroll
        for (int g = 0; g < 4; ++g) {
            const unsigned* P = pk[g >> 1];
            int base = (g & 1) * 4;
            unsigned s0 = hh ? P[base + 0] : P[base + 2];
            unsigned s1 = hh ? P[base + 1] : P[base + 3];
            unsigned r0 = (unsigned)__shfl_xor((int)s0, 32);
            unsigned r1 = (unsigned)__shfl_xor((int)s1, 32);
            union { unsigned u[4]; bf16x8 v; } bb;
            bb.u[0] = hh ? r0 : P[base + 0];
            bb.u[1] = hh ? r1 : P[base + 1];
            bb.u[2] = hh ? P[base + 2] : r0;
            bb.u[3] = hh ? P[base + 3] : r1;
            bf16x8 va0 = *(const bf16x8*)&Vl[curo + qc * 72 + g * 16 + hh * 8];
            bf16x8 va1 = *(const bf16x8*)&Vl[curo + (32 + qc) * 72 + g * 16 + hh * 8];
            ot0 = __builtin_amdgcn_mfma_f32_32x32x16_bf16(va0, bb.v, ot0, 0, 0, 0);
            ot1 = __builtin_amdgcn_mfma_f32_32x32x16_bf16(va1, bb.v, ot1, 0, 0, 0);
        }
    }

    // ---- finish l (other half of keys lives in the xor-32 partner)
    lsum += __shfl_xor(lsum, 32);
    float inv = 1.0f / lsum;

    // ---- stage O [q][d] into SMEM (reuses K/V space), coalesced store
    __syncthreads();
    int qlocal = w * 32 + qc;
#pragma unroll
    for (int dt = 0; dt < 2; ++dt) {
        const f32x16& o = dt ? ot1 : ot0;
#pragma unroll
        for (int g = 0; g < 4; ++g) {
            uint2 p;
            p.x = pack2(o[4 * g + 0] * inv, o[4 * g + 1] * inv);
            p.y = pack2(o[4 * g + 2] * inv, o[4 * g + 3] * inv);
            *(uint2*)&SMEM[qlocal * 72 + dt * 32 + g * 8 + hh * 4] = p;
        }
    }
    __syncthreads();
    unsigned short* ob = Xattn + (size_t)(n * SEQ + q0) * EMBED + h16 * HD;
#pragma unroll
    for (int i = 0; i < 4; ++i) {
        int idx = tid + i * 512;                 // 256 rows x 8 chunks
        int row = idx >> 3, ch = idx & 7;
        *(uint4*)(ob + (size_t)row * EMBED + ch * 8) = *(const uint4*)&SMEM[row * 72 + ch * 8];
    }
}

// ----------------------------------------------------- out = Xattn@Wo^T + bo
__global__ __launch_bounds__(256) void outproj_kernel(
    const unsigned short* __restrict__ X, const unsigned short* __restrict__ Wb,
    const float* __restrict__ bo, float* __restrict__ out)
{
    __shared__ __align__(16) unsigned short Al[128 * 72];
    __shared__ __align__(16) unsigned short Bl[128 * 72];

    int bx = blockIdx.x;
    int cm = bx >> 3, cn = bx & 7;
    int m0 = cm * 128, c0 = cn * 128;
    int tid = threadIdx.x;
    int w = tid >> 6, lane = tid & 63, ln = lane & 15, qd = lane >> 4;
    int rh = (w & 1) * 64, chh = (w >> 1) * 64;

    f32x4 acc[4][4];
    const f32x4 fz = {0.f, 0.f, 0.f, 0.f};
#pragma unroll
    for (int mt = 0; mt < 4; ++mt)
#pragma unroll
        for (int nt = 0; nt < 4; ++nt) acc[mt][nt] = fz;

    for (int k0 = 0; k0 < EMBED; k0 += 64) {
        for (int i = 0; i < 4; ++i) {
            int idx = tid + i * 256;
            int row = idx >> 3, ch = idx & 7;
            uint4 av = *(const uint4*)(X  + (size_t)(m0 + row) * EMBED + k0 + ch * 8);
            uint4 bv = *(const uint4*)(Wb + (size_t)(c0 + row) * EMBED + k0 + ch * 8);
            *(uint4*)&Al[row * 72 + ch * 8] = av;
            *(uint4*)&Bl[row * 72 + ch * 8] = bv;
        }
        __syncthreads();
        bf16x8 af[4][2], bf_[4][2];
#pragma unroll
        for (int mt = 0; mt < 4; ++mt)
#pragma unroll
            for (int kt = 0; kt < 2; ++kt)
                af[mt][kt] = *(const bf16x8*)&Al[(rh + mt * 16 + ln) * 72 + kt * 32 + qd * 8];
#pragma unroll
        for (int nt = 0; nt < 4; ++nt)
#pragma unroll
            for (int kt = 0; kt < 2; ++kt)
                bf_[nt][kt] = *(const bf16x8*)&Bl[(chh + nt * 16 + ln) * 72 + kt * 32 + qd * 8];
#pragma unroll
        for (int mt = 0; mt < 4; ++mt)
#pragma unroll
            for (int nt = 0; nt < 4; ++nt) {
                acc[mt][nt] = __builtin_amdgcn_mfma_f32_16x16x32_bf16(af[mt][0], bf_[nt][0], acc[mt][nt], 0, 0, 0);
                acc[mt][nt] = __builtin_amdgcn_mfma_f32_16x16x32_bf16(af[mt][1], bf_[nt][1], acc[mt][nt], 0, 0, 0);
            }
        __syncthreads();
    }

#pragma unroll
    for (int nt = 0; nt < 4; ++nt) {
        int col = c0 + chh + nt * 16 + ln;
        float bias = bo[col];
#pragma unroll
        for (int mt = 0; mt < 4; ++mt) {
            int row = m0 + rh + mt * 16 + qd * 4;
#pragma unroll
            for (int rg = 0; rg < 4; ++rg)
                out[(size_t)(row + rg) * EMBED + col] = acc[mt][nt][rg] + bias;
        }
    }
}

// --------------------------------------------------------------------- launch
extern "C" void kernel_launch(void* const* d_in, const int* in_sizes, int n_in,
                              void* d_out, int out_size, void* d_ws, size_t ws_size,
                              hipStream_t stream) {
    const float* values = (const float*)d_in[0];
    const float* keys   = (const float*)d_in[1];
    const float* query  = (const float*)d_in[2];
    const float* Wv     = (const float*)d_in[3];
    const float* Wk     = (const float*)d_in[4];
    const float* Wq     = (const float*)d_in[5];
    const float* Wo     = (const float*)d_in[6];
    const float* bo     = (const float*)d_in[7];
    float* out = (float*)d_out;

    unsigned short* ws = (unsigned short*)d_ws;
    const size_t HSZ = (size_t)NB * HEADS * SEQ * HD;   // 8388608 elems
    unsigned short* Qp = ws;
    unsigned short* Kp = Qp + HSZ;
    unsigned short* Vt = Kp + HSZ;
    unsigned short* Xa = Vt + HSZ;
    unsigned short* Wb = Xa + HSZ;                       // 1024*1024 elems

    cvt_kernel<<<1024, 256, 0, stream>>>(Wo, (unsigned*)Wb);
    proj_kernel<<<1536, 256, 0, stream>>>(query, keys, values, Wq, Wk, Wv, Qp, Kp, Vt);
    attn_kernel<<<512, 512, 0, stream>>>(Qp, Kp, Vt, Xa);
    outproj_kernel<<<512, 256, 0, stream>>>(Xa, Wb, bo, out);
}